// Round 6
// baseline (322.208 us; speedup 1.0000x reference)
//
#include <hip/hip_runtime.h>

#define N_NODES 50000
#define FEAT    64
#define HID     128
#define N_EDGES 640000
#define NBLK    196            // csr kernel blocks (all co-resident: 196 < 256 CUs)
#define GSZ     (NBLK * 256)
#define GCAP    64             // per-node staged index capacity

typedef __attribute__((ext_vector_type(8))) short bf16x8;
typedef __attribute__((ext_vector_type(4))) float f32x4;

static __device__ __forceinline__ unsigned short f2bf(float f) {
    unsigned u = __float_as_uint(f);
    u = u + 0x7fffu + ((u >> 16) & 1u);          // RNE
    return (unsigned short)(u >> 16);
}

// all-atomic sense-free grid barrier (monotone generation). bar[0]=arrivals,
// bar[1]=released generation. All ops are device-scope atomics -> cross-XCD safe.
static __device__ __forceinline__ void gridbar(int* bar, int gen) {
    __syncthreads();
    if (threadIdx.x == 0) {
        __threadfence();
        int arrived = atomicAdd(&bar[0], 1);
        if (arrived == NBLK - 1) {
            atomicExch(&bar[0], 0);
            __threadfence();
            atomicExch(&bar[1], gen);
        } else {
            while (atomicAdd(&bar[1], 0) < gen) __builtin_amdgcn_s_sleep(2);
        }
        __threadfence();
    }
    __syncthreads();
}

// ---------------- fused: zero + cvt + hist + scan + fill + permute ---------
__global__ __launch_bounds__(256) void csr_kernel(
        const int* __restrict__ src, const int* __restrict__ dst,
        const float* __restrict__ emb,
        const float* __restrict__ W1l, const float* __restrict__ W1r,
        const float* __restrict__ W2l, const float* __restrict__ W2r,
        int* count, int* offset, int* cursor, int* dhist, int* dcur,
        int* bsum, int* boff, int* dstart, int* perm, int* esrc,
        unsigned* emb_bf_u, unsigned* Wbf_u, int* bar) {
    __shared__ int tmp[256];
    __shared__ int lh[64];
    __shared__ int lb2[64];
    int t = threadIdx.x;
    int gtid = blockIdx.x * 256 + t;

    // ---- phase 0: zero counters + fp32->bf16 conversions ----
    for (int i = gtid; i < 100128; i += GSZ) count[i] = 0;   // count..dcur run
    for (int i = gtid; i < N_NODES * FEAT / 2; i += GSZ) {
        float2 v = ((const float2*)emb)[i];
        emb_bf_u[i] = ((unsigned)f2bf(v.y) << 16) | (unsigned)f2bf(v.x);
    }
    for (int p = gtid; p < 24576; p += GSZ) {                // 49152 weight elems
        int w = p * 2;
        float lo, hi;
        if (w < 8192)       { lo = W1l[w];         hi = W1l[w + 1]; }
        else if (w < 16384) { lo = W1r[w - 8192];  hi = W1r[w - 8191]; }
        else if (w < 32768) { lo = W2l[w - 16384]; hi = W2l[w - 16383]; }
        else                { lo = W2r[w - 32768]; hi = W2r[w - 32767]; }
        Wbf_u[p] = ((unsigned)f2bf(hi) << 16) | (unsigned)f2bf(lo);
    }
    gridbar(bar, 1);

    // ---- phase 1: degree histogram ----
    for (int e = gtid; e < N_EDGES; e += GSZ) atomicAdd(&count[dst[e]], 1);
    gridbar(bar, 2);

    // ---- phase 2: per-block scan of count + degree histogram ----
    {
        if (t < 64) lh[t] = 0;
        int v = (gtid < N_NODES) ? count[gtid] : 0;
        tmp[t] = v;
        __syncthreads();
        if (gtid < N_NODES) atomicAdd(&lh[v < 63 ? v : 63], 1);
        for (int off = 1; off < 256; off <<= 1) {
            int add = (t >= off) ? tmp[t - off] : 0;
            __syncthreads();
            tmp[t] += add;
            __syncthreads();
        }
        if (gtid < N_NODES) offset[gtid] = tmp[t] - v;
        if (t == 255) bsum[blockIdx.x] = tmp[255];
        if (t < 64 && lh[t] > 0) atomicAdd(&dhist[t], lh[t]);
    }
    gridbar(bar, 3);

    // ---- phase 3: scan block sums (block 0) + degree starts (block 1) ----
    if (blockIdx.x < 2) {
        const int* in  = (blockIdx.x == 0) ? bsum : dhist;
        int*       out = (blockIdx.x == 0) ? boff : dstart;
        int cnt        = (blockIdx.x == 0) ? NBLK : 64;
        int v = (t < cnt) ? in[t] : 0;
        tmp[t] = v;
        __syncthreads();
        for (int off = 1; off < 256; off <<= 1) {
            int add = (t >= off) ? tmp[t - off] : 0;
            __syncthreads();
            tmp[t] += add;
            __syncthreads();
        }
        if (t < cnt) out[t] = tmp[t] - v;
    }
    gridbar(bar, 4);

    // ---- phase 4: offset fixup ----
    if (gtid < N_NODES) offset[gtid] += boff[blockIdx.x];
    if (gtid == 0) offset[N_NODES] = N_EDGES;
    gridbar(bar, 5);

    // ---- phase 5: fill CSR + degree-sorted permutation ----
    for (int e = gtid; e < N_EDGES; e += GSZ) {
        int d = dst[e];
        int slot = atomicAdd(&cursor[d], 1);
        esrc[offset[d] + slot] = src[e];
    }
    {
        if (t < 64) lh[t] = 0;
        __syncthreads();
        int d = 0, slot = 0;
        if (gtid < N_NODES) {
            int c = count[gtid];
            d = c < 63 ? c : 63;
            slot = atomicAdd(&lh[d], 1);
        }
        __syncthreads();
        if (t < 64 && lh[t] > 0) lb2[t] = atomicAdd(&dcur[t], lh[t]);
        __syncthreads();
        if (gtid < N_NODES) perm[dstart[d] + lb2[d] + slot] = gtid;
    }
}

// ---------------- gather 1: mean of emb_bf16 rows (64 feats = 128 B) -------
// 4 waves/block, 8 nodes/wave (8 lanes x float4/row), degree-sorted order.
__global__ __launch_bounds__(256) void gather1_kernel(
        const float4* __restrict__ emb4, const int* __restrict__ offset,
        const int* __restrict__ esrc, const int* __restrict__ perm,
        uint4* __restrict__ mean1_u4) {
    __shared__ int sidx[4][8][GCAP];
    int t = threadIdx.x, wave = t >> 6, lane = t & 63;
    int sub = lane >> 3, fl = lane & 7;
    int widx = blockIdx.x * 32 + wave * 8 + sub;
    bool valid = widx < N_NODES;
    int n = 0, beg = 0, deg = 0;
    if (valid) { n = perm[widx]; beg = offset[n]; deg = offset[n + 1] - beg; }
    bool fast = deg <= GCAP;
    if (valid && fast) {
        for (int j = fl; j < deg; j += 8) sidx[wave][sub][j] = esrc[beg + j];
    }
    __syncthreads();
    float a[8] = {0.f,0.f,0.f,0.f,0.f,0.f,0.f,0.f};
    if (valid) {
        #define ACC1(v) { \
            unsigned ux=__float_as_uint((v).x),uy=__float_as_uint((v).y); \
            unsigned uz=__float_as_uint((v).z),uw=__float_as_uint((v).w); \
            a[0]+=__uint_as_float(ux<<16); a[1]+=__uint_as_float(ux&0xffff0000u); \
            a[2]+=__uint_as_float(uy<<16); a[3]+=__uint_as_float(uy&0xffff0000u); \
            a[4]+=__uint_as_float(uz<<16); a[5]+=__uint_as_float(uz&0xffff0000u); \
            a[6]+=__uint_as_float(uw<<16); a[7]+=__uint_as_float(uw&0xffff0000u); }
        if (fast) {
            int i = 0;
            for (; i + 8 <= deg; i += 8) {
                float4 v0 = emb4[sidx[wave][sub][i+0]*8+fl];
                float4 v1 = emb4[sidx[wave][sub][i+1]*8+fl];
                float4 v2 = emb4[sidx[wave][sub][i+2]*8+fl];
                float4 v3 = emb4[sidx[wave][sub][i+3]*8+fl];
                float4 v4 = emb4[sidx[wave][sub][i+4]*8+fl];
                float4 v5 = emb4[sidx[wave][sub][i+5]*8+fl];
                float4 v6 = emb4[sidx[wave][sub][i+6]*8+fl];
                float4 v7 = emb4[sidx[wave][sub][i+7]*8+fl];
                ACC1(v0) ACC1(v1) ACC1(v2) ACC1(v3)
                ACC1(v4) ACC1(v5) ACC1(v6) ACC1(v7)
            }
            for (; i + 4 <= deg; i += 4) {
                float4 v0 = emb4[sidx[wave][sub][i+0]*8+fl];
                float4 v1 = emb4[sidx[wave][sub][i+1]*8+fl];
                float4 v2 = emb4[sidx[wave][sub][i+2]*8+fl];
                float4 v3 = emb4[sidx[wave][sub][i+3]*8+fl];
                ACC1(v0) ACC1(v1) ACC1(v2) ACC1(v3)
            }
            for (; i < deg; ++i) { float4 v = emb4[sidx[wave][sub][i]*8+fl]; ACC1(v) }
        } else {
            for (int i = 0; i < deg; ++i) { float4 v = emb4[esrc[beg+i]*8+fl]; ACC1(v) }
        }
        float dinv = 1.0f / fmaxf((float)deg, 1.0f);
        uint4 o;
        o.x = ((unsigned)f2bf(a[1]*dinv) << 16) | (unsigned)f2bf(a[0]*dinv);
        o.y = ((unsigned)f2bf(a[3]*dinv) << 16) | (unsigned)f2bf(a[2]*dinv);
        o.z = ((unsigned)f2bf(a[5]*dinv) << 16) | (unsigned)f2bf(a[4]*dinv);
        o.w = ((unsigned)f2bf(a[7]*dinv) << 16) | (unsigned)f2bf(a[6]*dinv);
        mean1_u4[n*8 + fl] = o;
    }
}

// ---------------- gather 2: mean of h_bf16 rows (128 feats = 256 B) --------
// 4 nodes/wave (16 lanes x float4/row), unroll 8.
__global__ __launch_bounds__(256) void gather2_kernel(
        const float4* __restrict__ h4, const int* __restrict__ offset,
        const int* __restrict__ esrc, const int* __restrict__ perm,
        uint4* __restrict__ mean2_u4) {
    __shared__ int sidx[4][4][GCAP];
    int t = threadIdx.x, wave = t >> 6, lane = t & 63;
    int sub = lane >> 4, fl = lane & 15;
    int widx = blockIdx.x * 16 + wave * 4 + sub;
    bool valid = widx < N_NODES;
    int n = 0, beg = 0, deg = 0;
    if (valid) { n = perm[widx]; beg = offset[n]; deg = offset[n + 1] - beg; }
    bool fast = deg <= GCAP;
    if (valid && fast) {
        for (int j = fl; j < deg; j += 16) sidx[wave][sub][j] = esrc[beg + j];
    }
    __syncthreads();
    float a[8] = {0.f,0.f,0.f,0.f,0.f,0.f,0.f,0.f};
    if (valid) {
        if (fast) {
            int i = 0;
            for (; i + 8 <= deg; i += 8) {
                float4 v0 = h4[sidx[wave][sub][i+0]*16+fl];
                float4 v1 = h4[sidx[wave][sub][i+1]*16+fl];
                float4 v2 = h4[sidx[wave][sub][i+2]*16+fl];
                float4 v3 = h4[sidx[wave][sub][i+3]*16+fl];
                float4 v4 = h4[sidx[wave][sub][i+4]*16+fl];
                float4 v5 = h4[sidx[wave][sub][i+5]*16+fl];
                float4 v6 = h4[sidx[wave][sub][i+6]*16+fl];
                float4 v7 = h4[sidx[wave][sub][i+7]*16+fl];
                ACC1(v0) ACC1(v1) ACC1(v2) ACC1(v3)
                ACC1(v4) ACC1(v5) ACC1(v6) ACC1(v7)
            }
            for (; i + 4 <= deg; i += 4) {
                float4 v0 = h4[sidx[wave][sub][i+0]*16+fl];
                float4 v1 = h4[sidx[wave][sub][i+1]*16+fl];
                float4 v2 = h4[sidx[wave][sub][i+2]*16+fl];
                float4 v3 = h4[sidx[wave][sub][i+3]*16+fl];
                ACC1(v0) ACC1(v1) ACC1(v2) ACC1(v3)
            }
            for (; i < deg; ++i) { float4 v = h4[sidx[wave][sub][i]*16+fl]; ACC1(v) }
        } else {
            for (int i = 0; i < deg; ++i) { float4 v = h4[esrc[beg+i]*16+fl]; ACC1(v) }
        }
        float dinv = 1.0f / fmaxf((float)deg, 1.0f);
        uint4 o;
        o.x = ((unsigned)f2bf(a[1]*dinv) << 16) | (unsigned)f2bf(a[0]*dinv);
        o.y = ((unsigned)f2bf(a[3]*dinv) << 16) | (unsigned)f2bf(a[2]*dinv);
        o.z = ((unsigned)f2bf(a[5]*dinv) << 16) | (unsigned)f2bf(a[4]*dinv);
        o.w = ((unsigned)f2bf(a[7]*dinv) << 16) | (unsigned)f2bf(a[6]*dinv);
        mean2_u4[n*16 + fl] = o;
    }
}

// ---------------- GEMM layer 1: h = relu(mean1@W1l^T + b1l + emb@W1r^T) ----
// bf16 MFMA 16x16x32; C/D: col=lane&15, row=quad*4+reg (verified m89/m91).
__global__ __launch_bounds__(256) void gemm1_kernel(
        const short* __restrict__ mean1, const short* __restrict__ embb,
        const short* __restrict__ Wl, const short* __restrict__ Wr,
        const float* __restrict__ bias, unsigned short* __restrict__ hout) {
    int wid = blockIdx.x * 4 + (threadIdx.x >> 6);
    if (wid >= N_NODES / 16) return;
    int lane = threadIdx.x & 63;
    int col = lane & 15, quad = lane >> 4;
    int m0 = wid * 16;
    f32x4 acc[8];
    #pragma unroll
    for (int nt = 0; nt < 8; ++nt) acc[nt] = (f32x4){0.f,0.f,0.f,0.f};
    #pragma unroll
    for (int kb = 0; kb < FEAT; kb += 32) {
        bf16x8 a = *(const bf16x8*)(mean1 + (m0 + col) * FEAT + kb + quad * 8);
        #pragma unroll
        for (int nt = 0; nt < 8; ++nt) {
            bf16x8 b = *(const bf16x8*)(Wl + (nt * 16 + col) * FEAT + kb + quad * 8);
            acc[nt] = __builtin_amdgcn_mfma_f32_16x16x32_bf16(a, b, acc[nt], 0, 0, 0);
        }
    }
    #pragma unroll
    for (int kb = 0; kb < FEAT; kb += 32) {
        bf16x8 a = *(const bf16x8*)(embb + (m0 + col) * FEAT + kb + quad * 8);
        #pragma unroll
        for (int nt = 0; nt < 8; ++nt) {
            bf16x8 b = *(const bf16x8*)(Wr + (nt * 16 + col) * FEAT + kb + quad * 8);
            acc[nt] = __builtin_amdgcn_mfma_f32_16x16x32_bf16(a, b, acc[nt], 0, 0, 0);
        }
    }
    #pragma unroll
    for (int nt = 0; nt < 8; ++nt) {
        float bv = bias[nt * 16 + col];
        #pragma unroll
        for (int r = 0; r < 4; ++r) {
            float v = fmaxf(acc[nt][r] + bv, 0.f);
            hout[(m0 + quad * 4 + r) * HID + nt * 16 + col] = f2bf(v);
        }
    }
}

// ---------------- GEMM layer 2: out = mean2@W2l^T + b2l + h@W2r^T ----------
__global__ __launch_bounds__(256) void gemm2_kernel(
        const short* __restrict__ mean2, const short* __restrict__ hbf,
        const short* __restrict__ Wl, const short* __restrict__ Wr,
        const float* __restrict__ bias, float* __restrict__ out) {
    int wid = blockIdx.x * 4 + (threadIdx.x >> 6);
    if (wid >= N_NODES / 16) return;
    int lane = threadIdx.x & 63;
    int col = lane & 15, quad = lane >> 4;
    int m0 = wid * 16;
    f32x4 acc[8];
    #pragma unroll
    for (int nt = 0; nt < 8; ++nt) acc[nt] = (f32x4){0.f,0.f,0.f,0.f};
    #pragma unroll
    for (int kb = 0; kb < HID; kb += 32) {
        bf16x8 a = *(const bf16x8*)(mean2 + (m0 + col) * HID + kb + quad * 8);
        #pragma unroll
        for (int nt = 0; nt < 8; ++nt) {
            bf16x8 b = *(const bf16x8*)(Wl + (nt * 16 + col) * HID + kb + quad * 8);
            acc[nt] = __builtin_amdgcn_mfma_f32_16x16x32_bf16(a, b, acc[nt], 0, 0, 0);
        }
    }
    #pragma unroll
    for (int kb = 0; kb < HID; kb += 32) {
        bf16x8 a = *(const bf16x8*)(hbf + (m0 + col) * HID + kb + quad * 8);
        #pragma unroll
        for (int nt = 0; nt < 8; ++nt) {
            bf16x8 b = *(const bf16x8*)(Wr + (nt * 16 + col) * HID + kb + quad * 8);
            acc[nt] = __builtin_amdgcn_mfma_f32_16x16x32_bf16(a, b, acc[nt], 0, 0, 0);
        }
    }
    #pragma unroll
    for (int nt = 0; nt < 8; ++nt) {
        float bv = bias[nt * 16 + col];
        #pragma unroll
        for (int r = 0; r < 4; ++r) {
            out[(m0 + quad * 4 + r) * HID + nt * 16 + col] = acc[nt][r] + bv;
        }
    }
}

extern "C" void kernel_launch(void* const* d_in, const int* in_sizes, int n_in,
                              void* d_out, int out_size, void* d_ws, size_t ws_size,
                              hipStream_t stream) {
    const int*   edge_index = (const int*)d_in[0];
    const float* emb        = (const float*)d_in[1];
    const float* W1l        = (const float*)d_in[2];
    const float* b1l        = (const float*)d_in[3];
    const float* W1r        = (const float*)d_in[4];
    const float* W2l        = (const float*)d_in[5];
    const float* b2l        = (const float*)d_in[6];
    const float* W2r        = (const float*)d_in[7];
    float* out = (float*)d_out;

    const int* src = edge_index;
    const int* dst = edge_index + N_EDGES;

    // ---- ws layout (int-indexed; bf16 regions 16B-aligned), ~42 MB ----
    int* iws    = (int*)d_ws;
    int* offset = iws;                        // 50001 (+pad)
    int* count  = iws + 50004;                // 50000  -- zeroed in-kernel
    int* cursor = iws + 100004;               // 50000  -- zeroed in-kernel
    int* dhist  = iws + 150004;               // 64     -- zeroed in-kernel
    int* dcur   = iws + 150068;               // 64     -- zeroed in-kernel
    int* bsum   = iws + 150132;               // 256
    int* boff   = iws + 150388;               // 256
    int* dstart = iws + 150644;               // 64
    int* bar    = iws + 150708;               // 2 (memset to 0)
    int* perm   = iws + 150712;               // 50000
    int* esrc   = iws + 200712;               // 640000 -> 840712
    unsigned short* W1l_bf = (unsigned short*)(iws + 840712);   // 8192 bf16
    unsigned short* W1r_bf = (unsigned short*)(iws + 844808);   // 8192
    unsigned short* W2l_bf = (unsigned short*)(iws + 848904);   // 16384
    unsigned short* W2r_bf = (unsigned short*)(iws + 857096);   // 16384
    unsigned short* Wbf    = W1l_bf;                            // contiguous 49152
    unsigned short* emb_bf = (unsigned short*)(iws + 865288);   // 3.2M bf16
    unsigned short* mean1  = (unsigned short*)(iws + 2465288);  // 3.2M bf16
    unsigned short* hbf    = (unsigned short*)(iws + 4065288);  // 6.4M bf16
    unsigned short* mean2  = (unsigned short*)(iws + 7265288);  // 6.4M bf16

    hipMemsetAsync(bar, 0, 2 * sizeof(int), stream);

    csr_kernel<<<NBLK, 256, 0, stream>>>(
        src, dst, emb, W1l, W1r, W2l, W2r,
        count, offset, cursor, dhist, dcur, bsum, boff, dstart, perm, esrc,
        (unsigned*)emb_bf, (unsigned*)Wbf, bar);

    gather1_kernel<<<(N_NODES + 31) / 32, 256, 0, stream>>>(
        (const float4*)emb_bf, offset, esrc, perm, (uint4*)mean1);
    gemm1_kernel<<<(N_NODES / 16 + 3) / 4, 256, 0, stream>>>(
        (const short*)mean1, (const short*)emb_bf,
        (const short*)W1l_bf, (const short*)W1r_bf, b1l, hbf);
    gather2_kernel<<<(N_NODES + 15) / 16, 256, 0, stream>>>(
        (const float4*)hbf, offset, esrc, perm, (uint4*)mean2);
    gemm2_kernel<<<(N_NODES / 16 + 3) / 4, 256, 0, stream>>>(
        (const short*)mean2, (const short*)hbf,
        (const short*)W2l_bf, (const short*)W2r_bf, b2l, out);
}

// Round 8
// 271.810 us; speedup vs baseline: 1.1854x; 1.1854x over previous
//
#include <hip/hip_runtime.h>

#define N_NODES 50000
#define FEAT    64
#define HID     128
#define N_EDGES 640000
#define NBLK    196            // scanperm blocks (all co-resident: 196 < 256 CUs)
#define GCAP    64             // per-node staged index capacity

typedef __attribute__((ext_vector_type(8))) short bf16x8;
typedef __attribute__((ext_vector_type(4))) float f32x4;

static __device__ __forceinline__ unsigned short f2bf(float f) {
    unsigned u = __float_as_uint(f);
    u = u + 0x7fffu + ((u >> 16) & 1u);          // RNE
    return (unsigned short)(u >> 16);
}

// all-atomic monotone-generation grid barrier (device-scope -> cross-XCD safe)
static __device__ __forceinline__ void gridbar(int* bar, int gen) {
    __syncthreads();
    if (threadIdx.x == 0) {
        __threadfence();
        int arrived = atomicAdd(&bar[0], 1);
        if (arrived == NBLK - 1) {
            atomicExch(&bar[0], 0);
            __threadfence();
            atomicExch(&bar[1], gen);
        } else {
            while (atomicAdd(&bar[1], 0) < gen) __builtin_amdgcn_s_sleep(2);
        }
        __threadfence();
    }
    __syncthreads();
}

// ---- hist (full grid, 640k threads) + bf16 conversions (independent) ------
__global__ __launch_bounds__(256) void histcvt_kernel(
        const int* __restrict__ dst, const float* __restrict__ emb,
        const float* __restrict__ W1l, const float* __restrict__ W1r,
        const float* __restrict__ W2l, const float* __restrict__ W2r,
        int* __restrict__ count,
        unsigned* __restrict__ emb_bf_u, unsigned* __restrict__ Wbf_u) {
    int gtid = blockIdx.x * 256 + threadIdx.x;
    if (gtid < N_EDGES) atomicAdd(&count[dst[gtid]], 1);
    for (int i = gtid; i < N_NODES * FEAT / 2; i += N_EDGES) {
        float2 v = ((const float2*)emb)[i];
        emb_bf_u[i] = ((unsigned)f2bf(v.y) << 16) | (unsigned)f2bf(v.x);
    }
    if (gtid < 24576) {                      // 49152 weight elems, paired
        int w = gtid * 2;
        float lo, hi;
        if (w < 8192)       { lo = W1l[w];         hi = W1l[w + 1]; }
        else if (w < 16384) { lo = W1r[w - 8192];  hi = W1r[w - 8191]; }
        else if (w < 32768) { lo = W2l[w - 16384]; hi = W2l[w - 16383]; }
        else                { lo = W2r[w - 32768]; hi = W2r[w - 32767]; }
        Wbf_u[gtid] = ((unsigned)f2bf(hi) << 16) | (unsigned)f2bf(lo);
    }
}

// ---- fused node-level scans + degree-sort permutation (196 blocks) --------
__global__ __launch_bounds__(256) void scanperm_kernel(
        const int* __restrict__ count, int* offset, int* dhist, int* dcur,
        int* bsum, int* boff, int* dstart, int* perm, int* bar) {
    __shared__ int tmp[256];
    __shared__ int lh[64];
    __shared__ int lb2[64];
    int t = threadIdx.x;
    int gtid = blockIdx.x * 256 + t;

    // phase 0: per-block scan of count + degree histogram
    {
        if (t < 64) lh[t] = 0;
        int v = (gtid < N_NODES) ? count[gtid] : 0;
        tmp[t] = v;
        __syncthreads();
        if (gtid < N_NODES) atomicAdd(&lh[v < 63 ? v : 63], 1);
        for (int off = 1; off < 256; off <<= 1) {
            int add = (t >= off) ? tmp[t - off] : 0;
            __syncthreads();
            tmp[t] += add;
            __syncthreads();
        }
        if (gtid < N_NODES) offset[gtid] = tmp[t] - v;
        if (t == 255) bsum[blockIdx.x] = tmp[255];
        if (t < 64 && lh[t] > 0) atomicAdd(&dhist[t], lh[t]);
    }
    gridbar(bar, 1);

    // phase 1: scan block sums (block 0) + degree starts (block 1)
    if (blockIdx.x < 2) {
        const int* in  = (blockIdx.x == 0) ? bsum : dhist;
        int*       out = (blockIdx.x == 0) ? boff : dstart;
        int cnt        = (blockIdx.x == 0) ? NBLK : 64;
        int v = (t < cnt) ? in[t] : 0;
        tmp[t] = v;
        __syncthreads();
        for (int off = 1; off < 256; off <<= 1) {
            int add = (t >= off) ? tmp[t - off] : 0;
            __syncthreads();
            tmp[t] += add;
            __syncthreads();
        }
        if (t < cnt) out[t] = tmp[t] - v;
    }
    gridbar(bar, 2);

    // phase 2: offset fixup + degree-sorted permutation
    if (gtid < N_NODES) offset[gtid] += boff[blockIdx.x];
    if (gtid == 0) offset[N_NODES] = N_EDGES;
    {
        if (t < 64) lh[t] = 0;
        __syncthreads();
        int d = 0, slot = 0;
        if (gtid < N_NODES) {
            int c = count[gtid];
            d = c < 63 ? c : 63;
            slot = atomicAdd(&lh[d], 1);
        }
        __syncthreads();
        if (t < 64 && lh[t] > 0) lb2[t] = atomicAdd(&dcur[t], lh[t]);
        __syncthreads();
        if (gtid < N_NODES) perm[dstart[d] + lb2[d] + slot] = gtid;
    }
}

// ---- CSR fill (full grid) -------------------------------------------------
__global__ void fill_kernel(const int* __restrict__ src, const int* __restrict__ dst,
                            const int* __restrict__ offset, int* __restrict__ cursor,
                            int* __restrict__ esrc) {
    int e = blockIdx.x * blockDim.x + threadIdx.x;
    if (e >= N_EDGES) return;
    int d = dst[e];
    int slot = atomicAdd(&cursor[d], 1);
    esrc[offset[d] + slot] = src[e];
}

// ---------------- gather 1: mean of emb_bf16 rows (64 feats = 128 B) -------
// 4 waves/block, 8 nodes/wave (8 lanes x float4/row), degree-sorted order.
__global__ __launch_bounds__(256) void gather1_kernel(
        const float4* __restrict__ emb4, const int* __restrict__ offset,
        const int* __restrict__ esrc, const int* __restrict__ perm,
        uint4* __restrict__ mean1_u4) {
    __shared__ int sidx[4][8][GCAP];
    int t = threadIdx.x, wave = t >> 6, lane = t & 63;
    int sub = lane >> 3, fl = lane & 7;
    int widx = blockIdx.x * 32 + wave * 8 + sub;
    bool valid = widx < N_NODES;
    int n = 0, beg = 0, deg = 0;
    if (valid) { n = perm[widx]; beg = offset[n]; deg = offset[n + 1] - beg; }
    bool fast = deg <= GCAP;
    if (valid && fast) {
        for (int j = fl; j < deg; j += 8) sidx[wave][sub][j] = esrc[beg + j];
    }
    __syncthreads();
    float a[8] = {0.f,0.f,0.f,0.f,0.f,0.f,0.f,0.f};
    if (valid) {
        #define ACC1(v) { \
            unsigned ux=__float_as_uint((v).x),uy=__float_as_uint((v).y); \
            unsigned uz=__float_as_uint((v).z),uw=__float_as_uint((v).w); \
            a[0]+=__uint_as_float(ux<<16); a[1]+=__uint_as_float(ux&0xffff0000u); \
            a[2]+=__uint_as_float(uy<<16); a[3]+=__uint_as_float(uy&0xffff0000u); \
            a[4]+=__uint_as_float(uz<<16); a[5]+=__uint_as_float(uz&0xffff0000u); \
            a[6]+=__uint_as_float(uw<<16); a[7]+=__uint_as_float(uw&0xffff0000u); }
        if (fast) {
            int i = 0;
            for (; i + 8 <= deg; i += 8) {
                float4 v0 = emb4[sidx[wave][sub][i+0]*8+fl];
                float4 v1 = emb4[sidx[wave][sub][i+1]*8+fl];
                float4 v2 = emb4[sidx[wave][sub][i+2]*8+fl];
                float4 v3 = emb4[sidx[wave][sub][i+3]*8+fl];
                float4 v4 = emb4[sidx[wave][sub][i+4]*8+fl];
                float4 v5 = emb4[sidx[wave][sub][i+5]*8+fl];
                float4 v6 = emb4[sidx[wave][sub][i+6]*8+fl];
                float4 v7 = emb4[sidx[wave][sub][i+7]*8+fl];
                ACC1(v0) ACC1(v1) ACC1(v2) ACC1(v3)
                ACC1(v4) ACC1(v5) ACC1(v6) ACC1(v7)
            }
            for (; i + 4 <= deg; i += 4) {
                float4 v0 = emb4[sidx[wave][sub][i+0]*8+fl];
                float4 v1 = emb4[sidx[wave][sub][i+1]*8+fl];
                float4 v2 = emb4[sidx[wave][sub][i+2]*8+fl];
                float4 v3 = emb4[sidx[wave][sub][i+3]*8+fl];
                ACC1(v0) ACC1(v1) ACC1(v2) ACC1(v3)
            }
            for (; i < deg; ++i) { float4 v = emb4[sidx[wave][sub][i]*8+fl]; ACC1(v) }
        } else {
            for (int i = 0; i < deg; ++i) { float4 v = emb4[esrc[beg+i]*8+fl]; ACC1(v) }
        }
        float dinv = 1.0f / fmaxf((float)deg, 1.0f);
        uint4 o;
        o.x = ((unsigned)f2bf(a[1]*dinv) << 16) | (unsigned)f2bf(a[0]*dinv);
        o.y = ((unsigned)f2bf(a[3]*dinv) << 16) | (unsigned)f2bf(a[2]*dinv);
        o.z = ((unsigned)f2bf(a[5]*dinv) << 16) | (unsigned)f2bf(a[4]*dinv);
        o.w = ((unsigned)f2bf(a[7]*dinv) << 16) | (unsigned)f2bf(a[6]*dinv);
        mean1_u4[n*8 + fl] = o;
    }
}

// ---------------- gather 2: mean of h_bf16 rows (128 feats = 256 B) --------
// 4 nodes/wave (16 lanes x float4/row), unroll 8.
__global__ __launch_bounds__(256) void gather2_kernel(
        const float4* __restrict__ h4, const int* __restrict__ offset,
        const int* __restrict__ esrc, const int* __restrict__ perm,
        uint4* __restrict__ mean2_u4) {
    __shared__ int sidx[4][4][GCAP];
    int t = threadIdx.x, wave = t >> 6, lane = t & 63;
    int sub = lane >> 4, fl = lane & 15;
    int widx = blockIdx.x * 16 + wave * 4 + sub;
    bool valid = widx < N_NODES;
    int n = 0, beg = 0, deg = 0;
    if (valid) { n = perm[widx]; beg = offset[n]; deg = offset[n + 1] - beg; }
    bool fast = deg <= GCAP;
    if (valid && fast) {
        for (int j = fl; j < deg; j += 16) sidx[wave][sub][j] = esrc[beg + j];
    }
    __syncthreads();
    float a[8] = {0.f,0.f,0.f,0.f,0.f,0.f,0.f,0.f};
    if (valid) {
        if (fast) {
            int i = 0;
            for (; i + 8 <= deg; i += 8) {
                float4 v0 = h4[sidx[wave][sub][i+0]*16+fl];
                float4 v1 = h4[sidx[wave][sub][i+1]*16+fl];
                float4 v2 = h4[sidx[wave][sub][i+2]*16+fl];
                float4 v3 = h4[sidx[wave][sub][i+3]*16+fl];
                float4 v4 = h4[sidx[wave][sub][i+4]*16+fl];
                float4 v5 = h4[sidx[wave][sub][i+5]*16+fl];
                float4 v6 = h4[sidx[wave][sub][i+6]*16+fl];
                float4 v7 = h4[sidx[wave][sub][i+7]*16+fl];
                ACC1(v0) ACC1(v1) ACC1(v2) ACC1(v3)
                ACC1(v4) ACC1(v5) ACC1(v6) ACC1(v7)
            }
            for (; i + 4 <= deg; i += 4) {
                float4 v0 = h4[sidx[wave][sub][i+0]*16+fl];
                float4 v1 = h4[sidx[wave][sub][i+1]*16+fl];
                float4 v2 = h4[sidx[wave][sub][i+2]*16+fl];
                float4 v3 = h4[sidx[wave][sub][i+3]*16+fl];
                ACC1(v0) ACC1(v1) ACC1(v2) ACC1(v3)
            }
            for (; i < deg; ++i) { float4 v = h4[sidx[wave][sub][i]*16+fl]; ACC1(v) }
        } else {
            for (int i = 0; i < deg; ++i) { float4 v = h4[esrc[beg+i]*16+fl]; ACC1(v) }
        }
        float dinv = 1.0f / fmaxf((float)deg, 1.0f);
        uint4 o;
        o.x = ((unsigned)f2bf(a[1]*dinv) << 16) | (unsigned)f2bf(a[0]*dinv);
        o.y = ((unsigned)f2bf(a[3]*dinv) << 16) | (unsigned)f2bf(a[2]*dinv);
        o.z = ((unsigned)f2bf(a[5]*dinv) << 16) | (unsigned)f2bf(a[4]*dinv);
        o.w = ((unsigned)f2bf(a[7]*dinv) << 16) | (unsigned)f2bf(a[6]*dinv);
        mean2_u4[n*16 + fl] = o;
    }
}

// ---------------- GEMM layer 1: h = relu(mean1@W1l^T + b1l + emb@W1r^T) ----
// bf16 MFMA 16x16x32; C/D: col=lane&15, row=quad*4+reg (verified m89/m91).
__global__ __launch_bounds__(256) void gemm1_kernel(
        const short* __restrict__ mean1, const short* __restrict__ embb,
        const short* __restrict__ Wl, const short* __restrict__ Wr,
        const float* __restrict__ bias, unsigned short* __restrict__ hout) {
    int wid = blockIdx.x * 4 + (threadIdx.x >> 6);
    if (wid >= N_NODES / 16) return;
    int lane = threadIdx.x & 63;
    int col = lane & 15, quad = lane >> 4;
    int m0 = wid * 16;
    f32x4 acc[8];
    #pragma unroll
    for (int nt = 0; nt < 8; ++nt) acc[nt] = (f32x4){0.f,0.f,0.f,0.f};
    #pragma unroll
    for (int kb = 0; kb < FEAT; kb += 32) {
        bf16x8 a = *(const bf16x8*)(mean1 + (m0 + col) * FEAT + kb + quad * 8);
        #pragma unroll
        for (int nt = 0; nt < 8; ++nt) {
            bf16x8 b = *(const bf16x8*)(Wl + (nt * 16 + col) * FEAT + kb + quad * 8);
            acc[nt] = __builtin_amdgcn_mfma_f32_16x16x32_bf16(a, b, acc[nt], 0, 0, 0);
        }
    }
    #pragma unroll
    for (int kb = 0; kb < FEAT; kb += 32) {
        bf16x8 a = *(const bf16x8*)(embb + (m0 + col) * FEAT + kb + quad * 8);
        #pragma unroll
        for (int nt = 0; nt < 8; ++nt) {
            bf16x8 b = *(const bf16x8*)(Wr + (nt * 16 + col) * FEAT + kb + quad * 8);
            acc[nt] = __builtin_amdgcn_mfma_f32_16x16x32_bf16(a, b, acc[nt], 0, 0, 0);
        }
    }
    #pragma unroll
    for (int nt = 0; nt < 8; ++nt) {
        float bv = bias[nt * 16 + col];
        #pragma unroll
        for (int r = 0; r < 4; ++r) {
            float v = fmaxf(acc[nt][r] + bv, 0.f);
            hout[(m0 + quad * 4 + r) * HID + nt * 16 + col] = f2bf(v);
        }
    }
}

// ---------------- GEMM layer 2: out = mean2@W2l^T + b2l + h@W2r^T ----------
__global__ __launch_bounds__(256) void gemm2_kernel(
        const short* __restrict__ mean2, const short* __restrict__ hbf,
        const short* __restrict__ Wl, const short* __restrict__ Wr,
        const float* __restrict__ bias, float* __restrict__ out) {
    int wid = blockIdx.x * 4 + (threadIdx.x >> 6);
    if (wid >= N_NODES / 16) return;
    int lane = threadIdx.x & 63;
    int col = lane & 15, quad = lane >> 4;
    int m0 = wid * 16;
    f32x4 acc[8];
    #pragma unroll
    for (int nt = 0; nt < 8; ++nt) acc[nt] = (f32x4){0.f,0.f,0.f,0.f};
    #pragma unroll
    for (int kb = 0; kb < HID; kb += 32) {
        bf16x8 a = *(const bf16x8*)(mean2 + (m0 + col) * HID + kb + quad * 8);
        #pragma unroll
        for (int nt = 0; nt < 8; ++nt) {
            bf16x8 b = *(const bf16x8*)(Wl + (nt * 16 + col) * HID + kb + quad * 8);
            acc[nt] = __builtin_amdgcn_mfma_f32_16x16x32_bf16(a, b, acc[nt], 0, 0, 0);
        }
    }
    #pragma unroll
    for (int kb = 0; kb < HID; kb += 32) {
        bf16x8 a = *(const bf16x8*)(hbf + (m0 + col) * HID + kb + quad * 8);
        #pragma unroll
        for (int nt = 0; nt < 8; ++nt) {
            bf16x8 b = *(const bf16x8*)(Wr + (nt * 16 + col) * HID + kb + quad * 8);
            acc[nt] = __builtin_amdgcn_mfma_f32_16x16x32_bf16(a, b, acc[nt], 0, 0, 0);
        }
    }
    #pragma unroll
    for (int nt = 0; nt < 8; ++nt) {
        float bv = bias[nt * 16 + col];
        #pragma unroll
        for (int r = 0; r < 4; ++r) {
            out[(m0 + quad * 4 + r) * HID + nt * 16 + col] = acc[nt][r] + bv;
        }
    }
}

extern "C" void kernel_launch(void* const* d_in, const int* in_sizes, int n_in,
                              void* d_out, int out_size, void* d_ws, size_t ws_size,
                              hipStream_t stream) {
    const int*   edge_index = (const int*)d_in[0];
    const float* emb        = (const float*)d_in[1];
    const float* W1l        = (const float*)d_in[2];
    const float* b1l        = (const float*)d_in[3];
    const float* W1r        = (const float*)d_in[4];
    const float* W2l        = (const float*)d_in[5];
    const float* b2l        = (const float*)d_in[6];
    const float* W2r        = (const float*)d_in[7];
    float* out = (float*)d_out;

    const int* src = edge_index;
    const int* dst = edge_index + N_EDGES;

    // ws layout (int-indexed; bf16 regions 16B-aligned), ~42 MB.
    // count..bar form one contiguous zeroed run [50004, 150136).
    int* iws    = (int*)d_ws;
    int* offset = iws;                        // 50001 (+pad)
    int* count  = iws + 50004;                // 50000 (zeroed)
    int* cursor = iws + 100004;               // 50000 (zeroed)
    int* dhist  = iws + 150004;               // 64 (zeroed)
    int* dcur   = iws + 150068;               // 64 (zeroed)
    int* bar    = iws + 150132;               // 4 (zeroed)
    int* bsum   = iws + 150136;               // 256
    int* boff   = iws + 150392;               // 256
    int* dstart = iws + 150648;               // 64
    int* perm   = iws + 150712;               // 50000
    int* esrc   = iws + 200712;               // 640000 -> 840712
    unsigned short* W1l_bf = (unsigned short*)(iws + 840712);   // 8192 bf16
    unsigned short* W1r_bf = (unsigned short*)(iws + 844808);   // 8192
    unsigned short* W2l_bf = (unsigned short*)(iws + 848904);   // 16384
    unsigned short* W2r_bf = (unsigned short*)(iws + 857096);   // 16384
    unsigned short* Wbf    = W1l_bf;                            // contiguous 49152
    unsigned short* emb_bf = (unsigned short*)(iws + 865288);   // 3.2M bf16
    unsigned short* mean1  = (unsigned short*)(iws + 2465288);  // 3.2M bf16
    unsigned short* hbf    = (unsigned short*)(iws + 4065288);  // 6.4M bf16
    unsigned short* mean2  = (unsigned short*)(iws + 7265288);  // 6.4M bf16

    (void)hipMemsetAsync(count, 0, (size_t)(150136 - 50004) * sizeof(int), stream);

    histcvt_kernel<<<(N_EDGES + 255) / 256, 256, 0, stream>>>(
        dst, emb, W1l, W1r, W2l, W2r, count, (unsigned*)emb_bf, (unsigned*)Wbf);
    scanperm_kernel<<<NBLK, 256, 0, stream>>>(
        count, offset, dhist, dcur, bsum, boff, dstart, perm, bar);
    fill_kernel<<<(N_EDGES + 255) / 256, 256, 0, stream>>>(
        src, dst, offset, cursor, esrc);

    gather1_kernel<<<(N_NODES + 31) / 32, 256, 0, stream>>>(
        (const float4*)emb_bf, offset, esrc, perm, (uint4*)mean1);
    gemm1_kernel<<<(N_NODES / 16 + 3) / 4, 256, 0, stream>>>(
        (const short*)mean1, (const short*)emb_bf,
        (const short*)W1l_bf, (const short*)W1r_bf, b1l, hbf);
    gather2_kernel<<<(N_NODES + 15) / 16, 256, 0, stream>>>(
        (const float4*)hbf, offset, esrc, perm, (uint4*)mean2);
    gemm2_kernel<<<(N_NODES / 16 + 3) / 4, 256, 0, stream>>>(
        (const short*)mean2, (const short*)hbf,
        (const short*)W2l_bf, (const short*)W2r_bf, b2l, out);
}

// Round 10
// 231.712 us; speedup vs baseline: 1.3906x; 1.1731x over previous
//
#include <hip/hip_runtime.h>

#define N_NODES 50000
#define FEAT    64
#define HID     128
#define N_EDGES 640000
#define NBLK    196            // scanperm blocks (all co-resident)
#define GCAP    64             // per-node staged index capacity

typedef __attribute__((ext_vector_type(8))) short bf16x8;
typedef __attribute__((ext_vector_type(4))) float f32x4;

static __device__ __forceinline__ unsigned short f2bf(float f) {
    unsigned u = __float_as_uint(f);
    u = u + 0x7fffu + ((u >> 16) & 1u);          // RNE
    return (unsigned short)(u >> 16);
}
static __device__ __forceinline__ float bflo(unsigned u) {
    return __uint_as_float(u << 16);
}
static __device__ __forceinline__ float bfhi(unsigned u) {
    return __uint_as_float(u & 0xffff0000u);
}

// all-atomic monotone-generation grid barrier (device-scope -> cross-XCD safe)
static __device__ __forceinline__ void gridbar(int* bar, int gen) {
    __syncthreads();
    if (threadIdx.x == 0) {
        __threadfence();
        int arrived = atomicAdd(&bar[0], 1);
        if (arrived == NBLK - 1) {
            atomicExch(&bar[0], 0);
            __threadfence();
            atomicExch(&bar[1], gen);
        } else {
            while (atomicAdd(&bar[1], 0) < gen) __builtin_amdgcn_s_sleep(2);
        }
        __threadfence();
    }
    __syncthreads();
}

// ---- hist (records per-edge slot -> fill needs no atomics) + bf16 cvt -----
__global__ __launch_bounds__(256) void histcvt_kernel(
        const int* __restrict__ dst, const float* __restrict__ emb,
        const float* __restrict__ W1l, const float* __restrict__ W1r,
        const float* __restrict__ W2l, const float* __restrict__ W2r,
        int* __restrict__ count, int* __restrict__ eslot,
        unsigned* __restrict__ emb_bf_u, unsigned* __restrict__ Wbf_u) {
    int gtid = blockIdx.x * 256 + threadIdx.x;
    if (gtid < N_EDGES) {
        int slot = atomicAdd(&count[dst[gtid]], 1);
        eslot[gtid] = slot;
    }
    for (int i = gtid; i < N_NODES * FEAT / 2; i += N_EDGES) {
        float2 v = ((const float2*)emb)[i];
        emb_bf_u[i] = ((unsigned)f2bf(v.y) << 16) | (unsigned)f2bf(v.x);
    }
    if (gtid < 24576) {                      // 49152 weight elems, paired
        int w = gtid * 2;
        float lo, hi;
        if (w < 8192)       { lo = W1l[w];         hi = W1l[w + 1]; }
        else if (w < 16384) { lo = W1r[w - 8192];  hi = W1r[w - 8191]; }
        else if (w < 32768) { lo = W2l[w - 16384]; hi = W2l[w - 16383]; }
        else                { lo = W2r[w - 32768]; hi = W2r[w - 32767]; }
        Wbf_u[gtid] = ((unsigned)f2bf(hi) << 16) | (unsigned)f2bf(lo);
    }
}

// ---- fused node-level scans + degree-sort permutation (196 blocks) --------
__global__ __launch_bounds__(256) void scanperm_kernel(
        const int* __restrict__ count, int* offset, int* dhist, int* dcur,
        int* bsum, int* boff, int* dstart, int* perm, int* bar) {
    __shared__ int tmp[256];
    __shared__ int lh[64];
    __shared__ int lb2[64];
    int t = threadIdx.x;
    int gtid = blockIdx.x * 256 + t;

    {   // phase 0: per-block scan of count + degree histogram
        if (t < 64) lh[t] = 0;
        int v = (gtid < N_NODES) ? count[gtid] : 0;
        tmp[t] = v;
        __syncthreads();
        if (gtid < N_NODES) atomicAdd(&lh[v < 63 ? v : 63], 1);
        for (int off = 1; off < 256; off <<= 1) {
            int add = (t >= off) ? tmp[t - off] : 0;
            __syncthreads();
            tmp[t] += add;
            __syncthreads();
        }
        if (gtid < N_NODES) offset[gtid] = tmp[t] - v;
        if (t == 255) bsum[blockIdx.x] = tmp[255];
        if (t < 64 && lh[t] > 0) atomicAdd(&dhist[t], lh[t]);
    }
    gridbar(bar, 1);

    // phase 1: scan block sums (block 0) + degree starts (block 1)
    if (blockIdx.x < 2) {
        const int* in  = (blockIdx.x == 0) ? bsum : dhist;
        int*       out = (blockIdx.x == 0) ? boff : dstart;
        int cnt        = (blockIdx.x == 0) ? NBLK : 64;
        int v = (t < cnt) ? in[t] : 0;
        tmp[t] = v;
        __syncthreads();
        for (int off = 1; off < 256; off <<= 1) {
            int add = (t >= off) ? tmp[t - off] : 0;
            __syncthreads();
            tmp[t] += add;
            __syncthreads();
        }
        if (t < cnt) out[t] = tmp[t] - v;
    }
    gridbar(bar, 2);

    // phase 2: offset fixup + degree-sorted permutation
    if (gtid < N_NODES) offset[gtid] += boff[blockIdx.x];
    if (gtid == 0) offset[N_NODES] = N_EDGES;
    {
        if (t < 64) lh[t] = 0;
        __syncthreads();
        int d = 0, slot = 0;
        if (gtid < N_NODES) {
            int c = count[gtid];
            d = c < 63 ? c : 63;
            slot = atomicAdd(&lh[d], 1);
        }
        __syncthreads();
        if (t < 64 && lh[t] > 0) lb2[t] = atomicAdd(&dcur[t], lh[t]);
        __syncthreads();
        if (gtid < N_NODES) perm[dstart[d] + lb2[d] + slot] = gtid;
    }
}

// ---- CSR fill: atomic-free (slot precomputed in histcvt) ------------------
__global__ void fill_kernel(const int* __restrict__ src, const int* __restrict__ dst,
                            const int* __restrict__ offset,
                            const int* __restrict__ eslot, int* __restrict__ esrc) {
    int e = blockIdx.x * blockDim.x + threadIdx.x;
    if (e >= N_EDGES) return;
    esrc[offset[dst[e]] + eslot[e]] = src[e];
}

// ---- fused layer 1: gather-mean (LDS) + dual MFMA GEMM + relu -------------
// block = 16 perm-consecutive nodes. Gather: 16 subgroups x 16 lanes, lane
// covers 4 feats (8 B/row; row = 16 uint2). GEMM: 4 waves x 2 N-tiles,
// mean A-frag from LDS (144 B row stride -> 2-way alias = free), root A-frag
// gathered global. C/D: col=lane&15, row=quad*4+reg (verified m89/m91).
__global__ __launch_bounds__(256) void fgemm1_kernel(
        const unsigned short* __restrict__ embb, const int* __restrict__ offset,
        const int* __restrict__ esrc, const int* __restrict__ perm,
        const short* __restrict__ Wl, const short* __restrict__ Wr,
        const float* __restrict__ bias, unsigned short* __restrict__ hout) {
    __shared__ unsigned short smean[16][72];   // 64 used + 8 pad
    __shared__ int sidx[16][GCAP];
    __shared__ int nid[16];
    int t = threadIdx.x;
    if (t < 16) nid[t] = perm[blockIdx.x * 16 + t];
    __syncthreads();

    int sub = t >> 4, fl = t & 15;
    int n = nid[sub];
    int beg = offset[n], deg = offset[n + 1] - beg;
    bool fast = deg <= GCAP;
    if (fast) { for (int j = fl; j < deg; j += 16) sidx[sub][j] = esrc[beg + j]; }
    // staging lanes == consuming lanes (same wave): in-order LDS, no sync needed
    float A0[4] = {0,0,0,0}, A1[4] = {0,0,0,0}, A2[4] = {0,0,0,0}, A3[4] = {0,0,0,0};
    const uint2* eb2 = (const uint2*)embb;     // 16 uint2 per 64-feat row
    {
        int i = 0;
        if (fast) {
            for (; i + 4 <= deg; i += 4) {
                uint2 v0 = eb2[(size_t)sidx[sub][i+0] * 16 + fl];
                uint2 v1 = eb2[(size_t)sidx[sub][i+1] * 16 + fl];
                uint2 v2 = eb2[(size_t)sidx[sub][i+2] * 16 + fl];
                uint2 v3 = eb2[(size_t)sidx[sub][i+3] * 16 + fl];
                A0[0]+=bflo(v0.x); A0[1]+=bfhi(v0.x); A0[2]+=bflo(v0.y); A0[3]+=bfhi(v0.y);
                A1[0]+=bflo(v1.x); A1[1]+=bfhi(v1.x); A1[2]+=bflo(v1.y); A1[3]+=bfhi(v1.y);
                A2[0]+=bflo(v2.x); A2[1]+=bfhi(v2.x); A2[2]+=bflo(v2.y); A2[3]+=bfhi(v2.y);
                A3[0]+=bflo(v3.x); A3[1]+=bfhi(v3.x); A3[2]+=bflo(v3.y); A3[3]+=bfhi(v3.y);
            }
            for (; i < deg; ++i) {
                uint2 v = eb2[(size_t)sidx[sub][i] * 16 + fl];
                A0[0]+=bflo(v.x); A0[1]+=bfhi(v.x); A0[2]+=bflo(v.y); A0[3]+=bfhi(v.y);
            }
        } else {
            for (; i < deg; ++i) {
                uint2 v = eb2[(size_t)esrc[beg + i] * 16 + fl];
                A0[0]+=bflo(v.x); A0[1]+=bfhi(v.x); A0[2]+=bflo(v.y); A0[3]+=bfhi(v.y);
            }
        }
    }
    float dinv = 1.0f / fmaxf((float)deg, 1.0f);
    float s0 = ((A0[0]+A1[0])+(A2[0]+A3[0])) * dinv;
    float s1 = ((A0[1]+A1[1])+(A2[1]+A3[1])) * dinv;
    float s2 = ((A0[2]+A1[2])+(A2[2]+A3[2])) * dinv;
    float s3 = ((A0[3]+A1[3])+(A2[3]+A3[3])) * dinv;
    uint2 o;
    o.x = ((unsigned)f2bf(s1) << 16) | (unsigned)f2bf(s0);
    o.y = ((unsigned)f2bf(s3) << 16) | (unsigned)f2bf(s2);
    *(uint2*)&smean[sub][fl * 4] = o;
    __syncthreads();

    int wave = t >> 6, lane = t & 63;
    int col = lane & 15, quad = lane >> 4;
    int ncol = nid[col];
    int nt0 = wave * 2, nt1 = nt0 + 1;
    f32x4 acc0 = (f32x4){0.f,0.f,0.f,0.f}, acc1 = (f32x4){0.f,0.f,0.f,0.f};
    #pragma unroll
    for (int kb = 0; kb < FEAT; kb += 32) {
        bf16x8 am = *(const bf16x8*)&smean[col][kb + quad * 8];
        bf16x8 ax = *(const bf16x8*)(embb + (size_t)ncol * FEAT + kb + quad * 8);
        bf16x8 bl0 = *(const bf16x8*)(Wl + (nt0 * 16 + col) * FEAT + kb + quad * 8);
        bf16x8 br0 = *(const bf16x8*)(Wr + (nt0 * 16 + col) * FEAT + kb + quad * 8);
        bf16x8 bl1 = *(const bf16x8*)(Wl + (nt1 * 16 + col) * FEAT + kb + quad * 8);
        bf16x8 br1 = *(const bf16x8*)(Wr + (nt1 * 16 + col) * FEAT + kb + quad * 8);
        acc0 = __builtin_amdgcn_mfma_f32_16x16x32_bf16(am, bl0, acc0, 0, 0, 0);
        acc0 = __builtin_amdgcn_mfma_f32_16x16x32_bf16(ax, br0, acc0, 0, 0, 0);
        acc1 = __builtin_amdgcn_mfma_f32_16x16x32_bf16(am, bl1, acc1, 0, 0, 0);
        acc1 = __builtin_amdgcn_mfma_f32_16x16x32_bf16(ax, br1, acc1, 0, 0, 0);
    }
    float bv0 = bias[nt0 * 16 + col];
    float bv1 = bias[nt1 * 16 + col];
    #pragma unroll
    for (int r = 0; r < 4; ++r) {
        int node = nid[quad * 4 + r];
        hout[(size_t)node * HID + nt0 * 16 + col] = f2bf(fmaxf(acc0[r] + bv0, 0.f));
        hout[(size_t)node * HID + nt1 * 16 + col] = f2bf(fmaxf(acc1[r] + bv1, 0.f));
    }
}

// ---- fused layer 2: gather-mean (LDS) + dual MFMA GEMM --------------------
// Rows 128 feats = 16 uint4 (16 B/lane); smean row stride 272 B (2-way alias).
__global__ __launch_bounds__(256) void fgemm2_kernel(
        const unsigned short* __restrict__ hbf, const int* __restrict__ offset,
        const int* __restrict__ esrc, const int* __restrict__ perm,
        const short* __restrict__ Wl, const short* __restrict__ Wr,
        const float* __restrict__ bias, float* __restrict__ out) {
    __shared__ unsigned short smean[16][136];  // 128 used + 8 pad
    __shared__ int sidx[16][GCAP];
    __shared__ int nid[16];
    int t = threadIdx.x;
    if (t < 16) nid[t] = perm[blockIdx.x * 16 + t];
    __syncthreads();

    int sub = t >> 4, fl = t & 15;
    int n = nid[sub];
    int beg = offset[n], deg = offset[n + 1] - beg;
    bool fast = deg <= GCAP;
    if (fast) { for (int j = fl; j < deg; j += 16) sidx[sub][j] = esrc[beg + j]; }
    float A0[8] = {0,0,0,0,0,0,0,0}, A1[8] = {0,0,0,0,0,0,0,0};
    float A2[8] = {0,0,0,0,0,0,0,0}, A3[8] = {0,0,0,0,0,0,0,0};
    const uint4* hb4 = (const uint4*)hbf;      // 16 uint4 per 128-feat row
    #define ACCU(A, v) { \
        A[0]+=bflo((v).x); A[1]+=bfhi((v).x); A[2]+=bflo((v).y); A[3]+=bfhi((v).y); \
        A[4]+=bflo((v).z); A[5]+=bfhi((v).z); A[6]+=bflo((v).w); A[7]+=bfhi((v).w); }
    {
        int i = 0;
        if (fast) {
            for (; i + 4 <= deg; i += 4) {
                uint4 v0 = hb4[(size_t)sidx[sub][i+0] * 16 + fl];
                uint4 v1 = hb4[(size_t)sidx[sub][i+1] * 16 + fl];
                uint4 v2 = hb4[(size_t)sidx[sub][i+2] * 16 + fl];
                uint4 v3 = hb4[(size_t)sidx[sub][i+3] * 16 + fl];
                ACCU(A0, v0) ACCU(A1, v1) ACCU(A2, v2) ACCU(A3, v3)
            }
            for (; i < deg; ++i) {
                uint4 v = hb4[(size_t)sidx[sub][i] * 16 + fl];
                ACCU(A0, v)
            }
        } else {
            for (; i < deg; ++i) {
                uint4 v = hb4[(size_t)esrc[beg + i] * 16 + fl];
                ACCU(A0, v)
            }
        }
    }
    #undef ACCU
    float dinv = 1.0f / fmaxf((float)deg, 1.0f);
    unsigned ow[4];
    #pragma unroll
    for (int k = 0; k < 4; ++k) {
        float lo = ((A0[2*k]+A1[2*k])+(A2[2*k]+A3[2*k])) * dinv;
        float hi = ((A0[2*k+1]+A1[2*k+1])+(A2[2*k+1]+A3[2*k+1])) * dinv;
        ow[k] = ((unsigned)f2bf(hi) << 16) | (unsigned)f2bf(lo);
    }
    uint4 o4 = {ow[0], ow[1], ow[2], ow[3]};
    *(uint4*)&smean[sub][fl * 8] = o4;
    __syncthreads();

    int wave = t >> 6, lane = t & 63;
    int col = lane & 15, quad = lane >> 4;
    int ncol = nid[col];
    int nt0 = wave * 2, nt1 = nt0 + 1;
    f32x4 acc0 = (f32x4){0.f,0.f,0.f,0.f}, acc1 = (f32x4){0.f,0.f,0.f,0.f};
    #pragma unroll
    for (int kb = 0; kb < HID; kb += 32) {
        bf16x8 am = *(const bf16x8*)&smean[col][kb + quad * 8];
        bf16x8 ax = *(const bf16x8*)(hbf + (size_t)ncol * HID + kb + quad * 8);
        bf16x8 bl0 = *(const bf16x8*)(Wl + (nt0 * 16 + col) * HID + kb + quad * 8);
        bf16x8 br0 = *(const bf16x8*)(Wr + (nt0 * 16 + col) * HID + kb + quad * 8);
        bf16x8 bl1 = *(const bf16x8*)(Wl + (nt1 * 16 + col) * HID + kb + quad * 8);
        bf16x8 br1 = *(const bf16x8*)(Wr + (nt1 * 16 + col) * HID + kb + quad * 8);
        acc0 = __builtin_amdgcn_mfma_f32_16x16x32_bf16(am, bl0, acc0, 0, 0, 0);
        acc0 = __builtin_amdgcn_mfma_f32_16x16x32_bf16(ax, br0, acc0, 0, 0, 0);
        acc1 = __builtin_amdgcn_mfma_f32_16x16x32_bf16(am, bl1, acc1, 0, 0, 0);
        acc1 = __builtin_amdgcn_mfma_f32_16x16x32_bf16(ax, br1, acc1, 0, 0, 0);
    }
    float bv0 = bias[nt0 * 16 + col];
    float bv1 = bias[nt1 * 16 + col];
    #pragma unroll
    for (int r = 0; r < 4; ++r) {
        int node = nid[quad * 4 + r];
        out[(size_t)node * HID + nt0 * 16 + col] = acc0[r] + bv0;
        out[(size_t)node * HID + nt1 * 16 + col] = acc1[r] + bv1;
    }
}

extern "C" void kernel_launch(void* const* d_in, const int* in_sizes, int n_in,
                              void* d_out, int out_size, void* d_ws, size_t ws_size,
                              hipStream_t stream) {
    const int*   edge_index = (const int*)d_in[0];
    const float* emb        = (const float*)d_in[1];
    const float* W1l        = (const float*)d_in[2];
    const float* b1l        = (const float*)d_in[3];
    const float* W1r        = (const float*)d_in[4];
    const float* W2l        = (const float*)d_in[5];
    const float* b2l        = (const float*)d_in[6];
    const float* W2r        = (const float*)d_in[7];
    float* out = (float*)d_out;

    const int* src = edge_index;
    const int* dst = edge_index + N_EDGES;

    // ws layout (int-indexed; bf16 regions 16B-aligned), ~25 MB.
    // count..bar = one contiguous zeroed run [50004, 100136).
    int* iws    = (int*)d_ws;
    int* offset = iws;                        // 50001 (pad to 50004)
    int* count  = iws + 50004;                // 50000 (zeroed)
    int* dhist  = iws + 100004;               // 64 (zeroed)
    int* dcur   = iws + 100068;               // 64 (zeroed)
    int* bar    = iws + 100132;               // 4 (zeroed)
    int* bsum   = iws + 100136;               // 256
    int* boff   = iws + 100392;               // 256
    int* dstart = iws + 100648;               // 64
    int* perm   = iws + 100712;               // 50000
    int* esrc   = iws + 150712;               // 640000 -> 790712
    int* eslot  = iws + 790712;               // 640000 -> 1430712
    unsigned short* W1l_bf = (unsigned short*)(iws + 1430712);  // 8192 bf16
    unsigned short* W1r_bf = (unsigned short*)(iws + 1434808);  // 8192
    unsigned short* W2l_bf = (unsigned short*)(iws + 1438904);  // 16384
    unsigned short* W2r_bf = (unsigned short*)(iws + 1447096);  // 16384
    unsigned short* Wbf    = W1l_bf;                            // contiguous 49152
    unsigned short* emb_bf = (unsigned short*)(iws + 1455288);  // 3.2M bf16
    unsigned short* hbf    = (unsigned short*)(iws + 3055288);  // 6.4M bf16

    (void)hipMemsetAsync(count, 0, (size_t)(100136 - 50004) * sizeof(int), stream);

    histcvt_kernel<<<(N_EDGES + 255) / 256, 256, 0, stream>>>(
        dst, emb, W1l, W1r, W2l, W2r, count, eslot,
        (unsigned*)emb_bf, (unsigned*)Wbf);
    scanperm_kernel<<<NBLK, 256, 0, stream>>>(
        count, offset, dhist, dcur, bsum, boff, dstart, perm, bar);
    fill_kernel<<<(N_EDGES + 255) / 256, 256, 0, stream>>>(
        src, dst, offset, eslot, esrc);

    fgemm1_kernel<<<N_NODES / 16, 256, 0, stream>>>(
        emb_bf, offset, esrc, perm,
        (const short*)W1l_bf, (const short*)W1r_bf, b1l, hbf);
    fgemm2_kernel<<<N_NODES / 16, 256, 0, stream>>>(
        hbf, offset, esrc, perm,
        (const short*)W2l_bf, (const short*)W2r_bf, b2l, out);
}